// Round 5
// baseline (105.142 us; speedup 1.0000x reference)
//
#include <hip/hip_runtime.h>

#define HH 16
#define TT 4096
#define DD 64

typedef __attribute__((ext_vector_type(4))) _Float16 half4;
typedef __attribute__((ext_vector_type(8))) _Float16 half8;
typedef __attribute__((ext_vector_type(4))) float float4v;

// One block = 8 waves x 16 q rows = 128 q rows of one head; grid 512 (2/CU).
// Double-buffered 64-key K/V tiles in LDS, ONE barrier per tile:
//   write buf[cur] (from regs prefetched last iter) -> barrier ->
//   issue loads(t+1) -> compute(t).
// LDS rows are unpadded 128 B with XOR slot swizzle (slot ^= row&7):
// wave writes are contiguous 1024 B (conflict-free), fragment b64 reads are
// 2 lanes/bank (free). K staged [key][d]; V staged transposed [d][key].
__global__ __launch_bounds__(512, 4) void pa_fwd(
    const float* __restrict__ qg, const float* __restrict__ kg,
    const float* __restrict__ vg, const int* __restrict__ cu,
    float* __restrict__ outg)
{
    __shared__ __align__(16) _Float16 Kl[2][64 * 64];
    __shared__ __align__(16) _Float16 Vl[2][64 * 64];

    const int tid  = threadIdx.x;
    const int lane = tid & 63;
    const int wave = tid >> 6;
    const int lr   = lane & 15;
    const int lg   = lane >> 4;

    // XCD swizzle: grid 512 = 8 XCD x 64 contiguous work items (2 heads/XCD)
    const int bswz = ((int)blockIdx.x & 7) * 64 + ((int)blockIdx.x >> 3);
    const int h    = bswz >> 5;
    const int qblk = (bswz & 31) << 7;     // 128 q rows per block
    const int q    = qblk + wave * 16 + lr;

    // per-row segment bounds (searchsorted semantics)
    int s = 0;
    while (cu[s + 1] <= q) ++s;
    const int lo = cu[s], hi = cu[s + 1];

    // block-level staging range
    int sb = 0;
    while (cu[sb + 1] <= qblk) ++sb;
    const int blo = cu[sb];
    while (cu[sb + 1] <= qblk + 127) ++sb;
    const int bhi = cu[sb + 1];

    const int wlo = __shfl(lo, 0);    // wave min key
    const int whi = __shfl(hi, 15);   // wave max key
    const int mlo = __shfl(lo, 15);   // max lo over wave rows
    const int mhi = __shfl(hi, 0);    // min hi over wave rows

    // Q fragment (B operand), pre-scaled by 1/sqrt(64)
    const float* qrow = qg + ((size_t)h * TT + q) * DD;
    half4 qf[4];
#pragma unroll
    for (int ds = 0; ds < 4; ++ds) {
        float4v t4 = *(const float4v*)(qrow + ds * 16 + lg * 4);
#pragma unroll
        for (int j = 0; j < 4; ++j) qf[ds][j] = (_Float16)(t4[j] * 0.125f);
    }

    const float* kh_ = kg + (size_t)h * TT * DD;
    const float* vh_ = vg + (size_t)h * TT * DD;

    // staging assignment: row r = tid>>3 (wave-contiguous 8 rows), slot = tid&7
    const int srow = tid >> 3;          // K: key row / V: d row (0..63)
    const int sslot = tid & 7;          // 16B slot within row
    const unsigned swrb = (unsigned)(srow * 128 + (((sslot ^ (srow & 7)) << 4)));

    // prefetch registers
    float4v kA, kB;
    float vv[8];

    const int t0 = blo & ~63;
#define ISSUE(KT)                                                              \
    {                                                                          \
        int krow = (KT) + srow; if (krow > TT - 1) krow = TT - 1;              \
        const float* kp = kh_ + (size_t)krow * DD + sslot * 8;                 \
        kA = *(const float4v*)kp;                                              \
        kB = *(const float4v*)(kp + 4);                                        \
        _Pragma("unroll")                                                      \
        for (int c = 0; c < 8; ++c) {                                          \
            int vrow = (KT) + sslot * 8 + c; if (vrow > TT - 1) vrow = TT - 1; \
            vv[c] = vh_[(size_t)vrow * DD + srow];                             \
        }                                                                      \
    }

    ISSUE(t0);

    float4v acc[4];
#pragma unroll
    for (int dt = 0; dt < 4; ++dt) acc[dt] = (float4v){0.f, 0.f, 0.f, 0.f};
    float m_run = -1e30f, lsum = 0.f;

    int cur = 0;
    for (int kt = t0; kt < bhi; kt += 64) {
        // ---- pack + write LDS buf[cur] (vmcnt wait covered by prev compute) ----
        {
            half8 hk;
#pragma unroll
            for (int j = 0; j < 4; ++j) { hk[j] = (_Float16)kA[j]; hk[4 + j] = (_Float16)kB[j]; }
            *(half8*)((char*)Kl[cur] + swrb) = hk;
            half8 hv;
#pragma unroll
            for (int c = 0; c < 8; ++c) hv[c] = (_Float16)vv[c];
            *(half8*)((char*)Vl[cur] + swrb) = hv;
        }
        __syncthreads();   // the ONLY barrier per tile

        if (kt + 64 < bhi) ISSUE(kt + 64);   // wave-uniform

        if (!(kt + 64 <= wlo || kt >= whi)) {
            const char* Kb = (const char*)Kl[cur];
            const char* Vb = (const char*)Vl[cur];

            // ---- QK^T: St[key][q] for 4 x 16-key quarters ----
            float st[4][4];
            const bool fullv = (kt >= mlo) && (kt + 64 <= mhi);  // wave-uniform
            const unsigned rsw = ((unsigned)(lr & 7)) << 4;
#pragma unroll
            for (int t = 0; t < 4; ++t) {
                float4v sa = (float4v){0.f, 0.f, 0.f, 0.f};
                const int key_r = t * 16 + lr;
#pragma unroll
                for (int ds = 0; ds < 4; ++ds) {
                    half4 kf = *(const half4*)(Kb + key_r * 128 +
                                               (((unsigned)(ds * 32 + lg * 8)) ^ rsw));
                    sa = __builtin_amdgcn_mfma_f32_16x16x16f16(kf, qf[ds], sa, 0, 0, 0);
                }
                if (fullv) {
#pragma unroll
                    for (int j = 0; j < 4; ++j) st[t][j] = sa[j];
                } else {
#pragma unroll
                    for (int j = 0; j < 4; ++j) {
                        const int key = kt + t * 16 + lg * 4 + j;
                        st[t][j] = (key >= lo && key < hi) ? sa[j] : -1e30f;
                    }
                }
            }

            // ---- online softmax (per q row = lr; reduce over lg via xor16/32) ----
            float tx = -1e30f;
#pragma unroll
            for (int t = 0; t < 4; ++t)
#pragma unroll
                for (int j = 0; j < 4; ++j) tx = fmaxf(tx, st[t][j]);
            tx = fmaxf(tx, __shfl_xor(tx, 16));
            tx = fmaxf(tx, __shfl_xor(tx, 32));
            const float mn = fmaxf(m_run, tx);
            const float a  = __expf(m_run - mn);
            // all-masked tile self-heals at first valid tile (a=0 wipes acc,l)

            half4 pb[4];
            float ps = 0.f;
#pragma unroll
            for (int t = 0; t < 4; ++t)
#pragma unroll
                for (int j = 0; j < 4; ++j) {
                    const float e = __expf(st[t][j] - mn);
                    ps += e;
                    pb[t][j] = (_Float16)e;
                }
            ps += __shfl_xor(ps, 16);
            ps += __shfl_xor(ps, 32);
            lsum = lsum * a + ps;
            m_run = mn;

#pragma unroll
            for (int dt = 0; dt < 4; ++dt)
#pragma unroll
                for (int j = 0; j < 4; ++j) acc[dt][j] *= a;

            // ---- PV: Ot += V^T * P^T; Vt[d][key] b64 reads, 2-way banks ----
#pragma unroll
            for (int t = 0; t < 4; ++t)
#pragma unroll
                for (int dt = 0; dt < 4; ++dt) {
                    half4 vf = *(const half4*)(Vb + (dt * 16 + lr) * 128 +
                                               (((unsigned)(t * 32 + lg * 8)) ^ rsw));
                    acc[dt] = __builtin_amdgcn_mfma_f32_16x16x16f16(vf, pb[t], acc[dt], 0, 0, 0);
                }
        }
        cur ^= 1;
    }

    const float inv = 1.0f / lsum;
    float* orow = outg + ((size_t)h * TT + q) * DD;
#pragma unroll
    for (int dt = 0; dt < 4; ++dt) {
        float4v o;
#pragma unroll
        for (int j = 0; j < 4; ++j) o[j] = acc[dt][j] * inv;
        *(float4v*)(orow + dt * 16 + lg * 4) = o;
    }
#undef ISSUE
}

extern "C" void kernel_launch(void* const* d_in, const int* in_sizes, int n_in,
                              void* d_out, int out_size, void* d_ws, size_t ws_size,
                              hipStream_t stream) {
    const float* q  = (const float*)d_in[0];
    const float* k  = (const float*)d_in[1];
    const float* v  = (const float*)d_in[2];
    const int*   cu = (const int*)d_in[3];
    float* out = (float*)d_out;

    dim3 grid(HH * (TT / 128));   // 512
    dim3 block(512);
    hipLaunchKernelGGL(pa_fwd, grid, block, 0, stream, q, k, v, cu, out);
}